// Round 4
// baseline (22.063 us; speedup 1.0000x reference)
//
#include <hip/hip_runtime.h>

// Problem: x [B=4, L=4096, D=256] fp32. Math reduction: scores[b,i,j]=s[b,i]
// is constant along the softmax axis -> softmax uniform over causal prefix ->
// out[b,i,:] = mean(x[b,0..i,:]) (causal cumulative mean). q is irrelevant.
//
// Lessons: R2 grid.sync ~50us/sync (never again); R3 3 nodes = ~10us overhead.
// Now 2 kernels:
//  K1 cap_sums 128 blk x 1024 thr: each block covers 32 rows as 4 planes of
//     8 rows; writes BOTH P8 (8-row chunk sums) and, via LDS reduce, P32
//     (32-row superchunk sums). One x read from HBM.
//  K3 cap_out  512 blk x 256 thr: exclusive base = <=127 P32 rows + <=3 P8
//     rows (L2-resident), in-chunk running prefix from x (L3-resident), emit.

#define LL    4096
#define DD4   64          // D/4 float4 columns per batch
#define COLS4 256         // (B*D)/4 float4 columns total
#define NSUP  128         // superchunks (32 rows each)
#define SUPR  32
#define NCH   512         // chunks (8 rows each)
#define CHR   8

__device__ __forceinline__ void f4add(float4& a, const float4 b) {
    a.x += b.x; a.y += b.y; a.z += b.z; a.w += b.w;
}

// K1: 128 blocks x 1024 threads (16 waves) = 2048 waves total.
// plane p = tid>>8 handles rows [c*32 + 8p, +8); t = tid&255 is the column.
__global__ __launch_bounds__(1024) void cap_sums(const float* __restrict__ x,
                                                 float4* __restrict__ P8,
                                                 float4* __restrict__ P32) {
    __shared__ float4 sm[4][COLS4];
    const int tid = threadIdx.x;
    const int p = tid >> 8, t = tid & 255;
    const int b = t >> 6, d4 = t & 63;
    const int c = blockIdx.x;
    const int l0 = c * SUPR + p * CHR;
    const float4* xb = reinterpret_cast<const float4*>(x) + (size_t)b * LL * DD4 + d4;
    float4 s = {0.f, 0.f, 0.f, 0.f};
#pragma unroll
    for (int k = 0; k < CHR; ++k) f4add(s, xb[(size_t)(l0 + k) * DD4]);
    P8[(c * 4 + p) * COLS4 + t] = s;
    sm[p][t] = s;
    __syncthreads();
    if (p == 0) {
        float4 g = sm[0][t];
        f4add(g, sm[1][t]); f4add(g, sm[2][t]); f4add(g, sm[3][t]);
        P32[c * COLS4 + t] = g;
    }
}

// K3: 512 blocks x 256 threads. Base from P32 (<=127 rows) + P8 (<=3 rows),
// then running prefix over its 8 x-rows (loaded first, L3-resident).
__global__ __launch_bounds__(256) void cap_out(const float* __restrict__ x,
                                               const float4* __restrict__ P8,
                                               const float4* __restrict__ P32,
                                               float* __restrict__ out) {
    const int t = threadIdx.x, c = blockIdx.x;
    const int b = t >> 6, d4 = t & 63;
    const size_t colbase = (size_t)b * LL * DD4 + d4;
    const float4* xb = reinterpret_cast<const float4*>(x) + colbase;
    const int l0 = c * CHR;

    // issue x loads first so they overlap the lookback
    float4 v[CHR];
#pragma unroll
    for (int k = 0; k < CHR; ++k) v[k] = xb[(size_t)(l0 + k) * DD4];

    const int SUP = c >> 2;               // completed superchunks before l0
    float4 r0 = {0.f,0.f,0.f,0.f}, r1 = {0.f,0.f,0.f,0.f};
#pragma unroll 4
    for (int j = 0; j + 1 < SUP; j += 2) {
        f4add(r0, P32[j * COLS4 + t]);
        f4add(r1, P32[(j + 1) * COLS4 + t]);
    }
    if (SUP & 1) f4add(r0, P32[(SUP - 1) * COLS4 + t]);
#pragma unroll
    for (int j = SUP * 4; j < c; ++j) f4add(r1, P8[j * COLS4 + t]);
    float4 run = r0; f4add(run, r1);

    float4* ob = reinterpret_cast<float4*>(out) + colbase;
#pragma unroll
    for (int k = 0; k < CHR; ++k) {
        f4add(run, v[k]);
        const float inv = 1.0f / (float)(l0 + k + 1);
        float4 o = {run.x * inv, run.y * inv, run.z * inv, run.w * inv};
        ob[(size_t)(l0 + k) * DD4] = o;
    }
}

extern "C" void kernel_launch(void* const* d_in, const int* in_sizes, int n_in,
                              void* d_out, int out_size, void* d_ws, size_t ws_size,
                              hipStream_t stream) {
    const float* x = (const float*)d_in[0];
    // d_in[1] (q) is mathematically irrelevant (softmax of constant row).
    float* out = (float*)d_out;
    float4* P8  = (float4*)d_ws;                  // 512*256*16B = 2 MiB
    float4* P32 = P8 + (size_t)NCH * COLS4;       // +512 KiB

    cap_sums<<<dim3(NSUP), dim3(1024), 0, stream>>>(x, P8, P32);
    cap_out <<<dim3(NCH),  dim3(256),  0, stream>>>(x, P8, P32, out);
}

// Round 7
// 21.865 us; speedup vs baseline: 1.0090x; 1.0090x over previous
//
#include <hip/hip_runtime.h>

// Problem: x [B=4, L=4096, D=256] fp32. Math reduction: scores[b,i,j]=s[b,i]
// is constant along the softmax axis -> softmax uniform over causal prefix ->
// out[b,i,:] = mean(x[b,0..i,:]) (causal cumulative mean). q is irrelevant.
//
// Ledger: R2 cooperative 1-node: dur 134.0, kernel 119.2 -> 14.8us non-kernel
// overhead. R3 3-node 21.3us; R4 2-node 22.1us. R6 FAILED: P8 loop started at
// b8 + n16*16 but b8 ALREADY equals n64*64 + n16*16 -> skipped chunks [b8,c)
// whenever n16>0 (absmax 0.166). Fixed: loop starts at b8. Structure:
//  K1 cap_sums 512x256: P8[512] chunk sums (one HBM x read, 2 blk/CU)
//  K2 cap_lvls   8x1024: S16[32] and S64[8] via planes + LDS (2 MB L2 read)
//  K3 cap_out  512x256: base = <=7 S64 + <=3 S16 + <=15 P8 (avg 12.5 loads,
//     L2-resident), x re-read (L3-resident, issued first), nontemporal out.

#define LL    4096
#define DD4   64          // D/4 float4 columns per batch
#define COLS4 256         // (B*D)/4 float4 columns total
#define NCH   512         // 8-row chunks
#define CHR   8

typedef float vfloat4 __attribute__((ext_vector_type(4)));

__device__ __forceinline__ void f4add(float4& a, const float4 b) {
    a.x += b.x; a.y += b.y; a.z += b.z; a.w += b.w;
}

// K1: per-chunk column sums; wave = 64 lanes x float4 = 1 KiB coalesced.
__global__ __launch_bounds__(256) void cap_sums(const float* __restrict__ x,
                                                float4* __restrict__ P8) {
    const int t = threadIdx.x, c = blockIdx.x;
    const int b = t >> 6, d4 = t & 63;
    const float4* xb = reinterpret_cast<const float4*>(x) + (size_t)b * LL * DD4 + d4;
    const int l0 = c * CHR;
    float4 s = {0.f, 0.f, 0.f, 0.f};
#pragma unroll
    for (int k = 0; k < CHR; ++k) f4add(s, xb[(size_t)(l0 + k) * DD4]);
    P8[c * COLS4 + t] = s;
}

// K2: two hierarchy levels in one kernel. Block g covers chunks [g*64,(g+1)*64)
// as 4 planes x 16 chunks. Plane sum -> S16, LDS reduce of planes -> S64.
__global__ __launch_bounds__(1024) void cap_lvls(const float4* __restrict__ P8,
                                                 float4* __restrict__ S16,
                                                 float4* __restrict__ S64) {
    __shared__ float4 sm[4][COLS4];
    const int tid = threadIdx.x;
    const int p = tid >> 8, t = tid & 255;
    const int g = blockIdx.x;
    const int cb = g * 64 + p * 16;
    float4 s0 = {0.f,0.f,0.f,0.f}, s1 = {0.f,0.f,0.f,0.f};
#pragma unroll
    for (int j = 0; j < 16; j += 2) {
        f4add(s0, P8[(cb + j)     * COLS4 + t]);
        f4add(s1, P8[(cb + j + 1) * COLS4 + t]);
    }
    f4add(s0, s1);
    S16[(g * 4 + p) * COLS4 + t] = s0;
    sm[p][t] = s0;
    __syncthreads();
    if (p == 0) {
        float4 v = sm[0][t];
        f4add(v, sm[1][t]); f4add(v, sm[2][t]); f4add(v, sm[3][t]);
        S64[g * COLS4 + t] = v;
    }
}

// K3: 3-level exclusive base (avg 12.5 float4 loads), prefix, emit (nt store).
// Coverage proof: S64 terms cover chunks [0, n64*64); S16 terms cover
// [n64*64, n64*64 + n16*16) = [.., b8); P8 loop covers [b8, c). Total [0, c).
__global__ __launch_bounds__(256) void cap_out(const float* __restrict__ x,
                                               const float4* __restrict__ P8,
                                               const float4* __restrict__ S16,
                                               const float4* __restrict__ S64,
                                               float* __restrict__ out) {
    const int t = threadIdx.x, c = blockIdx.x;
    const int b = t >> 6, d4 = t & 63;
    const size_t colbase = (size_t)b * LL * DD4 + d4;
    const float4* xb = reinterpret_cast<const float4*>(x) + colbase;
    const int l0 = c * CHR;

    // issue x loads first (L3-resident) to overlap the lookback
    float4 v[CHR];
#pragma unroll
    for (int k = 0; k < CHR; ++k) v[k] = xb[(size_t)(l0 + k) * DD4];

    const int n64 = c >> 6;               // completed 512-row supergroups
    const int b16 = n64 << 2;             // first S16 index in current group
    const int n16 = (c >> 4) & 3;         // completed 128-row groups within
    const int b8  = (c >> 4) << 4;        // == n64*64 + n16*16 (first P8 chunk)
    float4 r0 = {0.f,0.f,0.f,0.f}, r1 = {0.f,0.f,0.f,0.f};
#pragma unroll
    for (int j = 0; j < 7; ++j)
        if (j < n64) f4add(r0, S64[j * COLS4 + t]);
#pragma unroll
    for (int j = 0; j < 3; ++j)
        if (j < n16) f4add(r1, S16[(b16 + j) * COLS4 + t]);
#pragma unroll 4
    for (int j = b8; j < c; ++j) f4add(r0, P8[j * COLS4 + t]);
    float4 run = r0; f4add(run, r1);

    vfloat4* ob = reinterpret_cast<vfloat4*>(out) + colbase;
#pragma unroll
    for (int k = 0; k < CHR; ++k) {
        f4add(run, v[k]);
        const float inv = 1.0f / (float)(l0 + k + 1);
        vfloat4 o = {run.x * inv, run.y * inv, run.z * inv, run.w * inv};
        __builtin_nontemporal_store(o, &ob[(size_t)(l0 + k) * DD4]);
    }
}

extern "C" void kernel_launch(void* const* d_in, const int* in_sizes, int n_in,
                              void* d_out, int out_size, void* d_ws, size_t ws_size,
                              hipStream_t stream) {
    const float* x = (const float*)d_in[0];
    // d_in[1] (q) is mathematically irrelevant (softmax of constant row).
    float* out = (float*)d_out;
    float4* P8  = (float4*)d_ws;                    // 2 MiB
    float4* S16 = P8  + (size_t)NCH * COLS4;        // +128 KiB
    float4* S64 = S16 + (size_t)32  * COLS4;        // +32 KiB

    cap_sums<<<dim3(NCH), dim3(256),  0, stream>>>(x, P8);
    cap_lvls<<<dim3(8),   dim3(1024), 0, stream>>>(P8, S16, S64);
    cap_out <<<dim3(NCH), dim3(256),  0, stream>>>(x, P8, S16, S64, out);
}